// Round 2
// baseline (3966.953 us; speedup 1.0000x reference)
//
#include <hip/hip_runtime.h>
#include <math.h>

// MLA forward, fp32 end-to-end (CDNA4 has no fp32 MFMA -> vector ALU path).
// Workspace layout (floats), total ~42.2M floats = ~169 MB:
//   h (4096x1024) | kR (4096x64) | qR (4096x1024) | q,k,v (4096x2048 each) | ao (4096x2048)

constexpr int BB  = 2;
constexpr int TT  = 2048;
constexpr int CCd = 2048;
constexpr int NHH = 16;
constexpr int DHH = 128;
constexpr int DHRR = 64;
constexpr int MM  = BB * TT;   // 4096 token rows

// ---------------------------------------------------------------------------
// RoPE rotate of 4 consecutive output columns starting at even column n0.
// Reference: theta_g = exp(-(g>>1)/d * ln(10000)); angle = (t+1)*theta.
// pairs are (even,odd) interleaved. Accurate expf/sincosf on purpose:
// angles reach ~2048 rad; fast-math range reduction would diverge from JAX.
template <int RD>
__device__ __forceinline__ float4 rope4(float4 v, int n0, int t) {
  const float kinv = 9.210340371976184f / (float)RD;  // ln(1e4)/d
  const float p0 = (float)(n0 >> 1);
  const float fr = (float)(t + 1);
  const float th0 = expf(-p0 * kinv);
  const float th1 = expf(-(p0 + 1.0f) * kinv);
  float s0, c0, s1, c1;
  sincosf(fr * th0, &s0, &c0);
  sincosf(fr * th1, &s1, &c1);
  return make_float4(v.x * c0 - v.y * s0, v.y * c0 + v.x * s0,
                     v.z * c1 - v.w * s1, v.w * c1 + v.z * s1);
}

// ---------------------------------------------------------------------------
// 128x128x16 fp32 GEMM, 256 threads, 8x8 micro-tile. C = A@W (+bias) (+RoPE).
// A: MxK row-major (lda), W: KxN row-major. M%128==0, N%128==0, K%16==0.
template <int RD>
__global__ __launch_bounds__(256) void gemm128_kernel(
    const float* __restrict__ A, int lda, const float* __restrict__ W,
    const float* __restrict__ bias, float* __restrict__ Co, int M, int N, int K) {
  __shared__ float As[16][132];  // [k][row], transposed store: 2-way bank alias only
  __shared__ float Bs[16][132];  // [k][col]
  const int tid = threadIdx.x;
  const int tx = tid & 15, ty = tid >> 4;
  const int bm = blockIdx.y * 128, bn = blockIdx.x * 128;
  const int ar = tid >> 1, akb = (tid & 1) * 8;   // A: 2 lanes/row, 8 k's each
  const int bkr = tid >> 4, bc = (tid & 15) * 8;  // B: 16 lanes/row, 8 cols each
  float acc[8][8] = {};

  for (int k0 = 0; k0 < K; k0 += 16) {
    const float* Ap = A + (size_t)(bm + ar) * lda + k0 + akb;
    const float4 a0 = *(const float4*)(Ap);
    const float4 a1 = *(const float4*)(Ap + 4);
    const float* Wp = W + (size_t)(k0 + bkr) * N + bn + bc;
    const float4 b0 = *(const float4*)(Wp);
    const float4 b1 = *(const float4*)(Wp + 4);
    __syncthreads();  // previous iter's LDS reads done before overwrite
    As[akb + 0][ar] = a0.x; As[akb + 1][ar] = a0.y;
    As[akb + 2][ar] = a0.z; As[akb + 3][ar] = a0.w;
    As[akb + 4][ar] = a1.x; As[akb + 5][ar] = a1.y;
    As[akb + 6][ar] = a1.z; As[akb + 7][ar] = a1.w;
    *(float4*)&Bs[bkr][bc] = b0;
    *(float4*)&Bs[bkr][bc + 4] = b1;
    __syncthreads();
#pragma unroll
    for (int k = 0; k < 16; ++k) {
      const float4 ra0 = *(const float4*)&As[k][ty * 8];
      const float4 ra1 = *(const float4*)&As[k][ty * 8 + 4];
      // cols split as {tx*4..+3} and {64+tx*4..+3}: conflict-free b128 reads
      const float4 rb0 = *(const float4*)&Bs[k][tx * 4];
      const float4 rb1 = *(const float4*)&Bs[k][64 + tx * 4];
      const float av[8] = {ra0.x, ra0.y, ra0.z, ra0.w, ra1.x, ra1.y, ra1.z, ra1.w};
      const float bv[8] = {rb0.x, rb0.y, rb0.z, rb0.w, rb1.x, rb1.y, rb1.z, rb1.w};
#pragma unroll
      for (int ii = 0; ii < 8; ++ii)
#pragma unroll
        for (int jj = 0; jj < 8; ++jj) acc[ii][jj] += av[ii] * bv[jj];
    }
  }

  const int c0 = bn + tx * 4, c1 = bn + 64 + tx * 4;
  float4 bi0 = make_float4(0.f, 0.f, 0.f, 0.f), bi1 = bi0;
  if (bias) {
    bi0 = *(const float4*)(bias + c0);
    bi1 = *(const float4*)(bias + c1);
  }
#pragma unroll
  for (int ii = 0; ii < 8; ++ii) {
    const int r = bm + ty * 8 + ii;
    const int t = r & (TT - 1);  // row = b*T + t
    float4 v0 = make_float4(acc[ii][0] + bi0.x, acc[ii][1] + bi0.y,
                            acc[ii][2] + bi0.z, acc[ii][3] + bi0.w);
    float4 v1 = make_float4(acc[ii][4] + bi1.x, acc[ii][5] + bi1.y,
                            acc[ii][6] + bi1.z, acc[ii][7] + bi1.w);
    if constexpr (RD != 0) {
      v0 = rope4<RD>(v0, c0, t);
      v1 = rope4<RD>(v1, c1, t);
    }
    float* Cp = Co + (size_t)r * N;
    *(float4*)(Cp + c0) = v0;
    *(float4*)(Cp + c1) = v1;
  }
}

// ---------------------------------------------------------------------------
// 64x64x16 fp32 GEMM (for N=64: kR = rope(h@WB + bB)), 4x4 micro-tile.
template <int RD>
__global__ __launch_bounds__(256) void gemm64_kernel(
    const float* __restrict__ A, int lda, const float* __restrict__ W,
    const float* __restrict__ bias, float* __restrict__ Co, int M, int N, int K) {
  __shared__ float As[16][68];
  __shared__ float Bs[16][68];
  const int tid = threadIdx.x;
  const int tx = tid & 15, ty = tid >> 4;
  const int bm = blockIdx.y * 64, bn = blockIdx.x * 64;
  float acc[4][4] = {};

  for (int k0 = 0; k0 < K; k0 += 16) {
    const float4 av = *(const float4*)(A + (size_t)(bm + (tid >> 2)) * lda + k0 + (tid & 3) * 4);
    const float4 bv = *(const float4*)(W + (size_t)(k0 + (tid >> 4)) * N + bn + (tid & 15) * 4);
    __syncthreads();
    const int ak = (tid & 3) * 4, arr = tid >> 2;
    As[ak + 0][arr] = av.x; As[ak + 1][arr] = av.y;
    As[ak + 2][arr] = av.z; As[ak + 3][arr] = av.w;
    *(float4*)&Bs[tid >> 4][(tid & 15) * 4] = bv;
    __syncthreads();
#pragma unroll
    for (int k = 0; k < 16; ++k) {
      const float4 a = *(const float4*)&As[k][ty * 4];
      const float4 b = *(const float4*)&Bs[k][tx * 4];
      const float avv[4] = {a.x, a.y, a.z, a.w};
      const float bvv[4] = {b.x, b.y, b.z, b.w};
#pragma unroll
      for (int ii = 0; ii < 4; ++ii)
#pragma unroll
        for (int jj = 0; jj < 4; ++jj) acc[ii][jj] += avv[ii] * bvv[jj];
    }
  }

  const int c0 = bn + tx * 4;
  float4 bi = make_float4(0.f, 0.f, 0.f, 0.f);
  if (bias) bi = *(const float4*)(bias + c0);
#pragma unroll
  for (int ii = 0; ii < 4; ++ii) {
    const int r = bm + ty * 4 + ii;
    const int t = r & (TT - 1);
    float4 v = make_float4(acc[ii][0] + bi.x, acc[ii][1] + bi.y,
                           acc[ii][2] + bi.z, acc[ii][3] + bi.w);
    if constexpr (RD != 0) v = rope4<RD>(v, c0, t);
    *(float4*)(Co + (size_t)r * N + c0) = v;
  }
}

// ---------------------------------------------------------------------------
// Flash attention, fp32. One block = one (b, h, 64-row q-tile). 256 threads.
// dk = 192 (128 nope + 64 rope), dv = 128, causal. Online softmax (m,l).
// LDS (dynamic, ~152 KB): Qs[192][68] d-major, Ks[192][68] d-major,
//                         Vs[64][132] row-major, Ps[64][68] (j-major).
__global__ __launch_bounds__(256) void flash_kernel(
    const float* __restrict__ qarr, const float* __restrict__ qRarr,
    const float* __restrict__ karr, const float* __restrict__ kRarr,
    const float* __restrict__ varr, float* __restrict__ oarr) {
  extern __shared__ float lds[];
  float* Qs = lds;              // 192*68
  float* Ks = Qs + 192 * 68;    // 192*68
  float* Vs = Ks + 192 * 68;    // 64*132
  float* Ps = Vs + 64 * 132;    // 64*68

  const int qi = (int)gridDim.x - 1 - (int)blockIdx.x;  // big tiles dispatch first
  const int bh = blockIdx.y;
  const int b = bh >> 4, hh = bh & 15;
  const int tid = threadIdx.x;
  const int tx = tid & 15, ty = tid >> 4;
  const int qt0 = qi * 64;
  const size_t rowbase = (size_t)b * TT;

  // ---- stage Q d-major (store pattern: row=tid>>2 varies with lanes -> 2-way alias)
  {
    const int r = tid >> 2, cb = tid & 3;
    const float* qrow  = qarr  + (rowbase + qt0 + r) * (NHH * DHH) + hh * DHH;
    const float* qRrow = qRarr + (rowbase + qt0 + r) * (NHH * DHRR) + hh * DHRR;
#pragma unroll
    for (int i = 0; i < 12; ++i) {
      const int d = (cb + i * 4) * 4;  // 0..188
      const float4 v4 = (d < DHH) ? *(const float4*)(qrow + d)
                                  : *(const float4*)(qRrow + (d - DHH));
      Qs[(d + 0) * 68 + r] = v4.x;
      Qs[(d + 1) * 68 + r] = v4.y;
      Qs[(d + 2) * 68 + r] = v4.z;
      Qs[(d + 3) * 68 + r] = v4.w;
    }
  }

  float o[4][8];
  float m_run[4], l_run[4];
#pragma unroll
  for (int ii = 0; ii < 4; ++ii) {
    m_run[ii] = -1e30f;
    l_run[ii] = 0.f;
#pragma unroll
    for (int c = 0; c < 8; ++c) o[ii][c] = 0.f;
  }

  const int nkt = qi + 1;  // causal: only tiles with kt0 <= qt0
  for (int kt = 0; kt < nkt; ++kt) {
    const int kt0 = kt * 64;
    __syncthreads();  // prev PV reads done (also covers Q staging on iter 0)
    {                 // ---- stage K d-major + V row-major
      const int r = tid >> 2, cb = tid & 3;
      const float* krow  = karr  + (rowbase + kt0 + r) * (NHH * DHH) + hh * DHH;
      const float* kRrow = kRarr + (rowbase + kt0 + r) * DHRR;
#pragma unroll
      for (int i = 0; i < 12; ++i) {
        const int d = (cb + i * 4) * 4;
        const float4 v4 = (d < DHH) ? *(const float4*)(krow + d)
                                    : *(const float4*)(kRrow + (d - DHH));
        Ks[(d + 0) * 68 + r] = v4.x;
        Ks[(d + 1) * 68 + r] = v4.y;
        Ks[(d + 2) * 68 + r] = v4.z;
        Ks[(d + 3) * 68 + r] = v4.w;
      }
      const float* vrow = varr + (rowbase + kt0 + r) * (NHH * DHH) + hh * DHH;
#pragma unroll
      for (int i = 0; i < 8; ++i) {
        const int d = (cb + i * 4) * 4;  // 0..124
        *(float4*)(Vs + r * 132 + d) = *(const float4*)(vrow + d);
      }
    }
    __syncthreads();

    // ---- S = Qf·Kf^T (64x64), thread: rows ty*4.., cols tx*4..
    float s[4][4] = {};
#pragma unroll 2
    for (int d = 0; d < 192; ++d) {
      const float4 a  = *(const float4*)(Qs + d * 68 + ty * 4);
      const float4 bq = *(const float4*)(Ks + d * 68 + tx * 4);
      const float avv[4] = {a.x, a.y, a.z, a.w};
      const float bvv[4] = {bq.x, bq.y, bq.z, bq.w};
#pragma unroll
      for (int ii = 0; ii < 4; ++ii)
#pragma unroll
        for (int jj = 0; jj < 4; ++jj) s[ii][jj] += avv[ii] * bvv[jj];
    }

    // ---- online softmax (rows owned by 16-lane tx-groups)
    const float scale = 0.07216878364870323f;  // 1/sqrt(192)
    const bool diag = (kt == qi);
#pragma unroll
    for (int ii = 0; ii < 4; ++ii) {
      const int lrow = ty * 4 + ii;
#pragma unroll
      for (int jj = 0; jj < 4; ++jj) {
        float sv = s[ii][jj] * scale;
        if (diag && (tx * 4 + jj > lrow)) sv = -1e30f;
        s[ii][jj] = sv;
      }
      float rmax = fmaxf(fmaxf(s[ii][0], s[ii][1]), fmaxf(s[ii][2], s[ii][3]));
      rmax = fmaxf(rmax, __shfl_xor(rmax, 1));
      rmax = fmaxf(rmax, __shfl_xor(rmax, 2));
      rmax = fmaxf(rmax, __shfl_xor(rmax, 4));
      rmax = fmaxf(rmax, __shfl_xor(rmax, 8));
      const float mnew = fmaxf(m_run[ii], rmax);
      const float alpha = __expf(m_run[ii] - mnew);
      m_run[ii] = mnew;
      float rsum = 0.f;
#pragma unroll
      for (int jj = 0; jj < 4; ++jj) {
        const float p = __expf(s[ii][jj] - mnew);
        Ps[(tx * 4 + jj) * 68 + lrow] = p;  // [j][i]
        rsum += p;
      }
      rsum += __shfl_xor(rsum, 1);
      rsum += __shfl_xor(rsum, 2);
      rsum += __shfl_xor(rsum, 4);
      rsum += __shfl_xor(rsum, 8);
      l_run[ii] = l_run[ii] * alpha + rsum;
#pragma unroll
      for (int c = 0; c < 8; ++c) o[ii][c] *= alpha;
    }
    __syncthreads();  // Ps visible

    // ---- O += P·V, thread: rows ty*4.., v-cols {tx*4, 64+tx*4}
    for (int j = 0; j < 64; ++j) {
      const float4 p4 = *(const float4*)(Ps + j * 68 + ty * 4);
      const float4 v0 = *(const float4*)(Vs + j * 132 + tx * 4);
      const float4 v1 = *(const float4*)(Vs + j * 132 + 64 + tx * 4);
      const float pv[4] = {p4.x, p4.y, p4.z, p4.w};
      const float vv[8] = {v0.x, v0.y, v0.z, v0.w, v1.x, v1.y, v1.z, v1.w};
#pragma unroll
      for (int ii = 0; ii < 4; ++ii)
#pragma unroll
        for (int c = 0; c < 8; ++c) o[ii][c] += pv[ii] * vv[c];
    }
  }

  // ---- epilogue: O/l -> (B*T, NH*128) at head hh
#pragma unroll
  for (int ii = 0; ii < 4; ++ii) {
    const float inv = 1.0f / l_run[ii];
    float* orow = oarr + (rowbase + qt0 + ty * 4 + ii) * (NHH * DHH) + hh * DHH;
    *(float4*)(orow + tx * 4) =
        make_float4(o[ii][0] * inv, o[ii][1] * inv, o[ii][2] * inv, o[ii][3] * inv);
    *(float4*)(orow + 64 + tx * 4) =
        make_float4(o[ii][4] * inv, o[ii][5] * inv, o[ii][6] * inv, o[ii][7] * inv);
  }
}

// ---------------------------------------------------------------------------
extern "C" void kernel_launch(void* const* d_in, const int* in_sizes, int n_in,
                              void* d_out, int out_size, void* d_ws, size_t ws_size,
                              hipStream_t stream) {
  const float* x   = (const float*)d_in[0];
  const float* WA  = (const float*)d_in[1];
  const float* bA  = (const float*)d_in[2];
  const float* WB  = (const float*)d_in[3];
  const float* bB  = (const float*)d_in[4];
  const float* WC  = (const float*)d_in[5];
  const float* bC  = (const float*)d_in[6];
  const float* WUQ = (const float*)d_in[7];
  const float* WUK = (const float*)d_in[8];
  const float* WUV = (const float*)d_in[9];
  const float* WZ  = (const float*)d_in[10];
  const float* bZ  = (const float*)d_in[11];
  float* out = (float*)d_out;

  // workspace partition (~169 MB)
  float* hbuf = (float*)d_ws;                    // (4096,1024)
  float* kR   = hbuf + (size_t)MM * 1024;        // (4096,64)
  float* qR   = kR + (size_t)MM * 64;            // (4096,1024)
  float* qb   = qR + (size_t)MM * 1024;          // (4096,2048)
  float* kb   = qb + (size_t)MM * 2048;          // (4096,2048)
  float* vb   = kb + (size_t)MM * 2048;          // (4096,2048)
  float* ao   = vb + (size_t)MM * 2048;          // (4096,2048)

  const dim3 thr(256);

  // 1. h = x @ WA + bA            (4096 x 1024, K=2048)
  gemm128_kernel<0><<<dim3(1024 / 128, MM / 128), thr, 0, stream>>>(
      x, CCd, WA, bA, hbuf, MM, 1024, 2048);
  // 2. kR = rope(h @ WB + bB), d=64   (4096 x 64, K=1024)
  gemm64_kernel<64><<<dim3(1, MM / 64), thr, 0, stream>>>(
      hbuf, 1024, WB, bB, kR, MM, 64, 1024);
  // 3. qR = rope(h @ WC + bC), d=1024 (4096 x 1024, K=1024)
  gemm128_kernel<1024><<<dim3(1024 / 128, MM / 128), thr, 0, stream>>>(
      hbuf, 1024, WC, bC, qR, MM, 1024, 1024);
  // 4. q = q_lat @ WUQ  (q_lat = h[:,512:], lda=1024)
  gemm128_kernel<0><<<dim3(2048 / 128, MM / 128), thr, 0, stream>>>(
      hbuf + 512, 1024, WUQ, nullptr, qb, MM, 2048, 512);
  // 5. k = kv_lat @ WUK (kv_lat = h[:,:512])
  gemm128_kernel<0><<<dim3(2048 / 128, MM / 128), thr, 0, stream>>>(
      hbuf, 1024, WUK, nullptr, kb, MM, 2048, 512);
  // 6. v = kv_lat @ WUV
  gemm128_kernel<0><<<dim3(2048 / 128, MM / 128), thr, 0, stream>>>(
      hbuf, 1024, WUV, nullptr, vb, MM, 2048, 512);
  // 7. flash attention -> ao (B*T, NH*128)
  const size_t flash_lds = (size_t)(192 * 68 + 192 * 68 + 64 * 132 + 64 * 68) * sizeof(float);
  (void)hipFuncSetAttribute(reinterpret_cast<const void*>(flash_kernel),
                            hipFuncAttributeMaxDynamicSharedMemorySize, (int)flash_lds);
  flash_kernel<<<dim3(TT / 64, BB * NHH), thr, flash_lds, stream>>>(
      qb, qR, kb, kR, vb, ao);
  // 8. out = ao @ WZ + bZ  (4096 x 2048, K=2048)
  gemm128_kernel<0><<<dim3(2048 / 128, MM / 128), thr, 0, stream>>>(
      ao, 2048, WZ, bZ, out, MM, 2048, 2048);
}

// Round 3
// 1438.146 us; speedup vs baseline: 2.7584x; 2.7584x over previous
//
#include <hip/hip_runtime.h>
#include <hip/hip_bf16.h>
#include <math.h>

// MLA forward. GEMMs: fp32 VALU (unchanged structure). Attention: bf16 MFMA
// (32x32x16), swapped-QK^T (S^T) so softmax is lane-local, P relayout via
// v_permlane32_swap_b32, V transposed in LDS for contiguous B-frags.
// q/qR pre-scaled by 1/sqrt(192) and stored bf16 by the GEMM epilogues.

constexpr int BB  = 2;
constexpr int TT  = 2048;
constexpr int CCd = 2048;
constexpr int NHH = 16;
constexpr int DHH = 128;
constexpr int DHRR = 64;
constexpr int MM  = BB * TT;
constexpr float QSCALE = 0.07216878364870323f;  // 1/sqrt(192)

typedef __attribute__((ext_vector_type(8))) short short8;
typedef __attribute__((ext_vector_type(16))) float f32x16;

__device__ __forceinline__ unsigned pk2(float lo, float hi) {
  // packs lo->low16, hi->high16 as bf16 RNE (compiler fuses to v_cvt_pk_bf16_f32)
  __hip_bfloat162 h = __float22bfloat162_rn(make_float2(lo, hi));
  union { __hip_bfloat162 b; unsigned u; } cv;
  cv.b = h;
  return cv.u;
}

// ---------------------------------------------------------------------------
// RoPE rotate of 4 consecutive output columns starting at even column n0.
// Reference: theta_g = exp(-(g>>1)/d * ln(10000)); angle = (t+1)*theta.
// Accurate expf/sincosf: angles reach ~2048 rad.
template <int RD>
__device__ __forceinline__ float4 rope4(float4 v, int n0, int t) {
  const float kinv = 9.210340371976184f / (float)RD;  // ln(1e4)/d
  const float p0 = (float)(n0 >> 1);
  const float fr = (float)(t + 1);
  const float th0 = expf(-p0 * kinv);
  const float th1 = expf(-(p0 + 1.0f) * kinv);
  float s0, c0, s1, c1;
  sincosf(fr * th0, &s0, &c0);
  sincosf(fr * th1, &s1, &c1);
  return make_float4(v.x * c0 - v.y * s0, v.y * c0 + v.x * s0,
                     v.z * c1 - v.w * s1, v.w * c1 + v.z * s1);
}

// OM: 0 = fp32 out, 1 = bf16 out, 2 = bf16 out scaled by QSCALE
template <int OM>
__device__ __forceinline__ void store4(void* Co, size_t r, int N, int c, float4 v) {
  if constexpr (OM == 0) {
    *(float4*)((float*)Co + r * (size_t)N + c) = v;
  } else {
    if constexpr (OM == 2) { v.x *= QSCALE; v.y *= QSCALE; v.z *= QSCALE; v.w *= QSCALE; }
    uint2 u = make_uint2(pk2(v.x, v.y), pk2(v.z, v.w));
    *(uint2*)((ushort*)Co + r * (size_t)N + c) = u;
  }
}

// ---------------------------------------------------------------------------
// 128x128x16 fp32 GEMM, 256 threads, 8x8 micro-tile. C = A@W (+bias)(+RoPE).
template <int RD, int OM>
__global__ __launch_bounds__(256) void gemm128_kernel(
    const float* __restrict__ A, int lda, const float* __restrict__ W,
    const float* __restrict__ bias, void* __restrict__ Co, int M, int N, int K) {
  __shared__ float As[16][132];
  __shared__ float Bs[16][132];
  const int tid = threadIdx.x;
  const int tx = tid & 15, ty = tid >> 4;
  const int bm = blockIdx.y * 128, bn = blockIdx.x * 128;
  const int ar = tid >> 1, akb = (tid & 1) * 8;
  const int bkr = tid >> 4, bc = (tid & 15) * 8;
  float acc[8][8] = {};

  for (int k0 = 0; k0 < K; k0 += 16) {
    const float* Ap = A + (size_t)(bm + ar) * lda + k0 + akb;
    const float4 a0 = *(const float4*)(Ap);
    const float4 a1 = *(const float4*)(Ap + 4);
    const float* Wp = W + (size_t)(k0 + bkr) * N + bn + bc;
    const float4 b0 = *(const float4*)(Wp);
    const float4 b1 = *(const float4*)(Wp + 4);
    __syncthreads();
    As[akb + 0][ar] = a0.x; As[akb + 1][ar] = a0.y;
    As[akb + 2][ar] = a0.z; As[akb + 3][ar] = a0.w;
    As[akb + 4][ar] = a1.x; As[akb + 5][ar] = a1.y;
    As[akb + 6][ar] = a1.z; As[akb + 7][ar] = a1.w;
    *(float4*)&Bs[bkr][bc] = b0;
    *(float4*)&Bs[bkr][bc + 4] = b1;
    __syncthreads();
#pragma unroll
    for (int k = 0; k < 16; ++k) {
      const float4 ra0 = *(const float4*)&As[k][ty * 8];
      const float4 ra1 = *(const float4*)&As[k][ty * 8 + 4];
      const float4 rb0 = *(const float4*)&Bs[k][tx * 4];
      const float4 rb1 = *(const float4*)&Bs[k][64 + tx * 4];
      const float av[8] = {ra0.x, ra0.y, ra0.z, ra0.w, ra1.x, ra1.y, ra1.z, ra1.w};
      const float bv[8] = {rb0.x, rb0.y, rb0.z, rb0.w, rb1.x, rb1.y, rb1.z, rb1.w};
#pragma unroll
      for (int ii = 0; ii < 8; ++ii)
#pragma unroll
        for (int jj = 0; jj < 8; ++jj) acc[ii][jj] += av[ii] * bv[jj];
    }
  }

  const int c0 = bn + tx * 4, c1 = bn + 64 + tx * 4;
  float4 bi0 = make_float4(0.f, 0.f, 0.f, 0.f), bi1 = bi0;
  if (bias) {
    bi0 = *(const float4*)(bias + c0);
    bi1 = *(const float4*)(bias + c1);
  }
#pragma unroll
  for (int ii = 0; ii < 8; ++ii) {
    const int r = bm + ty * 8 + ii;
    const int t = r & (TT - 1);
    float4 v0 = make_float4(acc[ii][0] + bi0.x, acc[ii][1] + bi0.y,
                            acc[ii][2] + bi0.z, acc[ii][3] + bi0.w);
    float4 v1 = make_float4(acc[ii][4] + bi1.x, acc[ii][5] + bi1.y,
                            acc[ii][6] + bi1.z, acc[ii][7] + bi1.w);
    if constexpr (RD != 0) {
      v0 = rope4<RD>(v0, c0, t);
      v1 = rope4<RD>(v1, c1, t);
    }
    store4<OM>(Co, (size_t)r, N, c0, v0);
    store4<OM>(Co, (size_t)r, N, c1, v1);
  }
}

// ---------------------------------------------------------------------------
// 64x64x16 fp32 GEMM (kR), 4x4 micro-tile.
template <int RD, int OM>
__global__ __launch_bounds__(256) void gemm64_kernel(
    const float* __restrict__ A, int lda, const float* __restrict__ W,
    const float* __restrict__ bias, void* __restrict__ Co, int M, int N, int K) {
  __shared__ float As[16][68];
  __shared__ float Bs[16][68];
  const int tid = threadIdx.x;
  const int tx = tid & 15, ty = tid >> 4;
  const int bm = blockIdx.y * 64, bn = blockIdx.x * 64;
  float acc[4][4] = {};

  for (int k0 = 0; k0 < K; k0 += 16) {
    const float4 av = *(const float4*)(A + (size_t)(bm + (tid >> 2)) * lda + k0 + (tid & 3) * 4);
    const float4 bv = *(const float4*)(W + (size_t)(k0 + (tid >> 4)) * N + bn + (tid & 15) * 4);
    __syncthreads();
    const int ak = (tid & 3) * 4, arr = tid >> 2;
    As[ak + 0][arr] = av.x; As[ak + 1][arr] = av.y;
    As[ak + 2][arr] = av.z; As[ak + 3][arr] = av.w;
    *(float4*)&Bs[tid >> 4][(tid & 15) * 4] = bv;
    __syncthreads();
#pragma unroll
    for (int k = 0; k < 16; ++k) {
      const float4 a = *(const float4*)&As[k][ty * 4];
      const float4 b = *(const float4*)&Bs[k][tx * 4];
      const float avv[4] = {a.x, a.y, a.z, a.w};
      const float bvv[4] = {b.x, b.y, b.z, b.w};
#pragma unroll
      for (int ii = 0; ii < 4; ++ii)
#pragma unroll
        for (int jj = 0; jj < 4; ++jj) acc[ii][jj] += avv[ii] * bvv[jj];
    }
  }

  const int c0 = bn + tx * 4;
  float4 bi = make_float4(0.f, 0.f, 0.f, 0.f);
  if (bias) bi = *(const float4*)(bias + c0);
#pragma unroll
  for (int ii = 0; ii < 4; ++ii) {
    const int r = bm + ty * 4 + ii;
    const int t = r & (TT - 1);
    float4 v = make_float4(acc[ii][0] + bi.x, acc[ii][1] + bi.y,
                           acc[ii][2] + bi.z, acc[ii][3] + bi.w);
    if constexpr (RD != 0) v = rope4<RD>(v, c0, t);
    store4<OM>(Co, (size_t)r, N, c0, v);
  }
}

// ---------------------------------------------------------------------------
// MFMA flash attention. Block = 256 thr = 4 waves; wave owns 32 q-rows
// (q-block 128). KVBLK=64, dk=192, dv=128, causal, online softmax.
// S^T = mfma(A=K, B=Q): C-layout col(lane&31)=q-row -> softmax lane-local.
// P relayout to A-frags via cvt_pk + v_permlane32_swap_b32 (2 swaps/K-step).
// LDS: Ks[64][200] bf16 (pad 8 -> bank-balanced b128), Vt[128][72] (V^T).
__global__ __launch_bounds__(256, 2) void flash_kernel(
    const ushort* __restrict__ qarr, const ushort* __restrict__ qRarr,
    const ushort* __restrict__ karr, const ushort* __restrict__ kRarr,
    const ushort* __restrict__ varr, float* __restrict__ oarr) {
  __shared__ ushort Ks[64][200];
  __shared__ ushort Vt[128][72];

  const int bi = (int)gridDim.x - 1 - (int)blockIdx.x;  // heavy q-blocks first
  const int qt0 = bi * 128;
  const int bh = blockIdx.y;
  const int b = bh >> 4, hh = bh & 15;
  const int tid = threadIdx.x;
  const int lane = tid & 63, wid = tid >> 6;
  const int l31 = lane & 31, hl = lane >> 5;
  const int qbase = qt0 + wid * 32;
  const size_t rowbase = (size_t)b * TT;

  // ---- Q fragments in registers (B-operand layout: lane holds Q[l31][16ks+8hl..+7])
  short8 qf[12];
  {
    const ushort* qp  = qarr  + (rowbase + qbase + l31) * 2048 + hh * 128;
    const ushort* qRp = qRarr + (rowbase + qbase + l31) * 1024 + hh * 64;
#pragma unroll
    for (int ks = 0; ks < 12; ++ks) {
      const int d = ks * 16 + hl * 8;
      const ushort* p = (d < 128) ? (qp + d) : (qRp + (d - 128));
      qf[ks] = *(const short8*)p;
    }
  }

  f32x16 oacc[4];
#pragma unroll
  for (int nt = 0; nt < 4; ++nt)
#pragma unroll
    for (int r = 0; r < 16; ++r) oacc[nt][r] = 0.f;
  float m_run = -1e30f, l_run = 0.f;

  const int nkt = 2 * bi + 2;
  for (int kt = 0; kt < nkt; ++kt) {
    const int kt0 = kt * 64;
    // ---- global -> regs (issued before barrier: latency hides under prev compute)
    short8 kreg[6], vreg[4];
    {
      const int r = tid >> 2, sub = tid & 3;
      const ushort* kp  = karr  + (rowbase + kt0 + r) * 2048 + hh * 128;
      const ushort* kRp = kRarr + (rowbase + kt0 + r) * 64;
#pragma unroll
      for (int c = 0; c < 6; ++c) {
        const int d0 = c * 32 + sub * 8;
        const ushort* p = (d0 < 128) ? (kp + d0) : (kRp + (d0 - 128));
        kreg[c] = *(const short8*)p;
      }
      const int vr = tid & 63, dblk = tid >> 6;
      const ushort* vp = varr + (rowbase + kt0 + vr) * 2048 + hh * 128 + dblk * 32;
#pragma unroll
      for (int c = 0; c < 4; ++c) vreg[c] = *(const short8*)(vp + c * 8);
    }
    __syncthreads();  // prev compute done reading LDS
    {
      const int r = tid >> 2, sub = tid & 3;
#pragma unroll
      for (int c = 0; c < 6; ++c) *(short8*)&Ks[r][c * 32 + sub * 8] = kreg[c];
      const int vr = tid & 63, dblk = tid >> 6;
#pragma unroll
      for (int c = 0; c < 4; ++c)
#pragma unroll
        for (int e = 0; e < 8; ++e)
          Vt[dblk * 32 + c * 8 + e][vr] = (ushort)vreg[c][e];  // merged 2B, conflict-free
    }
    __syncthreads();

    if (kt0 < qbase + 32) {  // wave has at least one unmasked (q,k) pair
      // ---- S^T: 2 M-tiles (kcols) x 12 K-steps
      f32x16 sa[2];
#pragma unroll
      for (int t2 = 0; t2 < 2; ++t2)
#pragma unroll
        for (int r = 0; r < 16; ++r) sa[t2][r] = 0.f;
#pragma unroll
      for (int ks = 0; ks < 12; ++ks) {
        const short8 ka0 = *(const short8*)&Ks[l31][ks * 16 + hl * 8];
        const short8 ka1 = *(const short8*)&Ks[32 + l31][ks * 16 + hl * 8];
        sa[0] = __builtin_amdgcn_mfma_f32_32x32x16_bf16(ka0, qf[ks], sa[0], 0, 0, 0);
        sa[1] = __builtin_amdgcn_mfma_f32_32x32x16_bf16(ka1, qf[ks], sa[1], 0, 0, 0);
      }
      // ---- causal mask (only diagonal-overlap tiles)
      if (kt0 + 63 > qbase) {
        const int qrow = qbase + l31;
#pragma unroll
        for (int t2 = 0; t2 < 2; ++t2)
#pragma unroll
          for (int r = 0; r < 16; ++r) {
            const int kcol = kt0 + t2 * 32 + (r & 3) + 8 * (r >> 2) + 4 * hl;
            if (kcol > qrow) sa[t2][r] = -1e30f;
          }
      }
      // ---- online softmax, lane-local (q = l31; halves hold complementary kcols)
      float pmax = -1e30f;
#pragma unroll
      for (int t2 = 0; t2 < 2; ++t2)
#pragma unroll
        for (int r = 0; r < 16; ++r) pmax = fmaxf(pmax, sa[t2][r]);
      pmax = fmaxf(pmax, __shfl_xor(pmax, 32));
      if (!__all(pmax <= m_run + 8.0f)) {  // defer-max (T13)
        const float mnew = fmaxf(m_run, pmax);
        const float alpha = __expf(m_run - mnew);
        m_run = mnew;
        l_run *= alpha;
#pragma unroll
        for (int r = 0; r < 16; ++r) {
          const int qr = (r & 3) + 8 * (r >> 2) + 4 * hl;
          const float al = __shfl(alpha, qr);  // lanes qr / qr+32 hold equal alpha
          oacc[0][r] *= al; oacc[1][r] *= al; oacc[2][r] *= al; oacc[3][r] *= al;
        }
      }
      float rsum = 0.f;
#pragma unroll
      for (int t2 = 0; t2 < 2; ++t2)
#pragma unroll
        for (int r = 0; r < 16; ++r) {
          const float p = __expf(sa[t2][r] - m_run);
          sa[t2][r] = p;
          rsum += p;
        }
      rsum += __shfl_xor(rsum, 32);
      l_run += rsum;
      // ---- P -> bf16 A-frags via permlane32_swap (word order: j(0,1)(2,3)(4,5)(6,7))
      short8 pf[4];
#pragma unroll
      for (int t2 = 0; t2 < 2; ++t2)
#pragma unroll
        for (int kb = 0; kb < 2; ++kb) {
          const int g = kb * 8;
          unsigned wa = pk2(sa[t2][g + 0], sa[t2][g + 1]);
          unsigned wb = pk2(sa[t2][g + 4], sa[t2][g + 5]);
          unsigned wc = pk2(sa[t2][g + 2], sa[t2][g + 3]);
          unsigned wd = pk2(sa[t2][g + 6], sa[t2][g + 7]);
          asm volatile("v_permlane32_swap_b32 %0, %1" : "+v"(wa), "+v"(wb));
          asm volatile("v_permlane32_swap_b32 %0, %1" : "+v"(wc), "+v"(wd));
          union { unsigned u[4]; short8 s; } cv;
          cv.u[0] = wa; cv.u[1] = wc; cv.u[2] = wb; cv.u[3] = wd;
          pf[t2 * 2 + kb] = cv.s;
        }
      // ---- O += P·V : 4 N-tiles (dv) x 4 K-steps (keys)
#pragma unroll
      for (int ks = 0; ks < 4; ++ks)
#pragma unroll
        for (int nt = 0; nt < 4; ++nt) {
          const short8 vf = *(const short8*)&Vt[nt * 32 + l31][ks * 16 + hl * 8];
          oacc[nt] = __builtin_amdgcn_mfma_f32_32x32x16_bf16(pf[ks], vf, oacc[nt], 0, 0, 0);
        }
    }
  }

  // ---- epilogue: rows spread over regs, cols = l31 (+32nt); fetch 1/l via shfl
  const float inv = 1.0f / l_run;
#pragma unroll
  for (int r = 0; r < 16; ++r) {
    const int qr = (r & 3) + 8 * (r >> 2) + 4 * hl;
    const float il = __shfl(inv, qr);
    float* orow = oarr + (rowbase + qbase + qr) * 2048 + hh * 128;
#pragma unroll
    for (int nt = 0; nt < 4; ++nt) orow[nt * 32 + l31] = oacc[nt][r] * il;
  }
}

// ---------------------------------------------------------------------------
extern "C" void kernel_launch(void* const* d_in, const int* in_sizes, int n_in,
                              void* d_out, int out_size, void* d_ws, size_t ws_size,
                              hipStream_t stream) {
  const float* x   = (const float*)d_in[0];
  const float* WA  = (const float*)d_in[1];
  const float* bA  = (const float*)d_in[2];
  const float* WB  = (const float*)d_in[3];
  const float* bB  = (const float*)d_in[4];
  const float* WC  = (const float*)d_in[5];
  const float* bC  = (const float*)d_in[6];
  const float* WUQ = (const float*)d_in[7];
  const float* WUK = (const float*)d_in[8];
  const float* WUV = (const float*)d_in[9];
  const float* WZ  = (const float*)d_in[10];
  const float* bZ  = (const float*)d_in[11];
  float* out = (float*)d_out;

  // workspace (bytes): h f32 | kR bf16 | qR bf16 | q,k,v bf16 | ao f32  (~110 MB)
  char* wsb = (char*)d_ws;
  float*  hbuf = (float*)wsb;                                   // 16 MB
  ushort* kR   = (ushort*)(wsb + (size_t)MM * 1024 * 4);        // +0.5 MB
  ushort* qR   = (ushort*)((char*)kR + (size_t)MM * 64 * 2);    // +8 MB
  ushort* qb   = (ushort*)((char*)qR + (size_t)MM * 1024 * 2);  // +16 MB
  ushort* kb   = (ushort*)((char*)qb + (size_t)MM * 2048 * 2);
  ushort* vb   = (ushort*)((char*)kb + (size_t)MM * 2048 * 2);
  float*  ao   = (float*)((char*)vb + (size_t)MM * 2048 * 2);   // 32 MB

  const dim3 thr(256);

  // 1. h = x @ WA + bA (fp32)
  gemm128_kernel<0, 0><<<dim3(1024 / 128, MM / 128), thr, 0, stream>>>(
      x, CCd, WA, bA, hbuf, MM, 1024, 2048);
  // 2. kR = rope64(h @ WB + bB) -> bf16
  gemm64_kernel<64, 1><<<dim3(1, MM / 64), thr, 0, stream>>>(
      hbuf, 1024, WB, bB, kR, MM, 64, 1024);
  // 3. qR = rope1024(h @ WC + bC) * qscale -> bf16
  gemm128_kernel<1024, 2><<<dim3(1024 / 128, MM / 128), thr, 0, stream>>>(
      hbuf, 1024, WC, bC, qR, MM, 1024, 1024);
  // 4. q = (q_lat @ WUQ) * qscale -> bf16
  gemm128_kernel<0, 2><<<dim3(2048 / 128, MM / 128), thr, 0, stream>>>(
      hbuf + 512, 1024, WUQ, nullptr, qb, MM, 2048, 512);
  // 5. k = kv_lat @ WUK -> bf16
  gemm128_kernel<0, 1><<<dim3(2048 / 128, MM / 128), thr, 0, stream>>>(
      hbuf, 1024, WUK, nullptr, kb, MM, 2048, 512);
  // 6. v = kv_lat @ WUV -> bf16
  gemm128_kernel<0, 1><<<dim3(2048 / 128, MM / 128), thr, 0, stream>>>(
      hbuf, 1024, WUV, nullptr, vb, MM, 2048, 512);
  // 7. MFMA flash attention -> ao (fp32)
  flash_kernel<<<dim3(TT / 128, BB * NHH), thr, 0, stream>>>(
      qb, qR, kb, kR, vb, ao);
  // 8. out = ao @ WZ + bZ (fp32)
  gemm128_kernel<0, 0><<<dim3(2048 / 128, MM / 128), thr, 0, stream>>>(
      ao, 2048, WZ, bZ, out, MM, 2048, 2048);
}

// Round 5
// 523.089 us; speedup vs baseline: 7.5837x; 2.7493x over previous
//
#include <hip/hip_runtime.h>
#include <hip/hip_bf16.h>
#include <math.h>

// MLA forward. All large GEMMs: bf16 MFMA (32x32x16, m97-style staging:
// global_load_lds w16 + T2 XOR swizzle via pre-swizzled global source).
// Attention: bf16 MFMA flash (round-3 structure, verified). fp32 accum
// everywhere; bf16 storage for intermediates.

constexpr int BB  = 2;
constexpr int TT  = 2048;
constexpr int NHH = 16;
constexpr int MM  = BB * TT;
constexpr float QSCALE = 0.07216878364870323f;  // 1/sqrt(192)

typedef __attribute__((ext_vector_type(8))) short short8;
typedef __attribute__((ext_vector_type(16))) float f32x16;

__device__ __forceinline__ unsigned pk2(float lo, float hi) {
  __hip_bfloat162 h = __float22bfloat162_rn(make_float2(lo, hi));
  union { __hip_bfloat162 b; unsigned u; } cv;
  cv.b = h;
  return cv.u;
}
__device__ __forceinline__ ushort bfu(float x) {
  union { __hip_bfloat16 b; ushort u; } cv;
  cv.b = __float2bfloat16(x);
  return cv.u;
}
__device__ __forceinline__ float bf2f(ushort u) {
  union { float f; unsigned i; } cv;
  cv.i = ((unsigned)u) << 16;
  return cv.f;
}
__device__ __forceinline__ void gload_lds16(const void* g, void* l) {
  __builtin_amdgcn_global_load_lds((const __attribute__((address_space(1))) void*)g,
                                   (__attribute__((address_space(3))) void*)l, 16, 0, 0);
}

// ---------------------------------------------------------------------------
// fp32 -> bf16 flat convert (n % 1024 == 0)
__global__ __launch_bounds__(256) void conv_kernel(const float* __restrict__ src,
                                                   ushort* __restrict__ dst) {
  const size_t i = ((size_t)blockIdx.x * 256 + threadIdx.x) * 4;
  const float4 v = *(const float4*)(src + i);
  uint2 u;
  u.x = pk2(v.x, v.y);
  u.y = pk2(v.z, v.w);
  *(uint2*)(dst + i) = u;
}

// fp32 [K][N] -> bf16 [N][K] transpose-convert. Grid (N/64, K/64), 256 thr.
__global__ __launch_bounds__(256) void tconv_kernel(const float* __restrict__ src,
                                                    ushort* __restrict__ dst,
                                                    int K, int N) {
  __shared__ ushort tile[64][72];
  const int k0 = blockIdx.y * 64, n0 = blockIdx.x * 64;
  const int t = threadIdx.x;
  const int r = t >> 4, c4 = (t & 15) * 4;
#pragma unroll
  for (int p = 0; p < 4; ++p) {
    const int k = r + p * 16;
    const float4 v = *(const float4*)(src + (size_t)(k0 + k) * N + n0 + c4);
    tile[c4 + 0][k] = bfu(v.x);
    tile[c4 + 1][k] = bfu(v.y);
    tile[c4 + 2][k] = bfu(v.z);
    tile[c4 + 3][k] = bfu(v.w);
  }
  __syncthreads();
#pragma unroll
  for (int p = 0; p < 4; ++p) {
    const int n = r + p * 16;
    ushort4 o;
    o.x = tile[n][c4 + 0];
    o.y = tile[n][c4 + 1];
    o.z = tile[n][c4 + 2];
    o.w = tile[n][c4 + 3];
    *(ushort4*)(dst + (size_t)(n0 + n) * K + k0 + c4) = o;
  }
}

// ---------------------------------------------------------------------------
// bf16 MFMA GEMM: C[M][N] = A[M][K] @ Bt[N][K]^T (+bias)(+RoPE)(+scale).
// 128x128 tile, BK=64, 4 waves x (2x2 of 32x32x16). LDS 32KB single-buffered,
// staged by global_load_lds(16B) with T2 swizzle (linear dest, pre-swizzled
// global src; frag reads XOR the same involution). 2 barriers per K-step.
// OM: 0 fp32 out, 1 bf16 out, 2 bf16*QSCALE out. RD: RoPE width (0 = none).
template <int RD, int OM>
__global__ __launch_bounds__(256) void gemm_mfma_kernel(
    const ushort* __restrict__ A, int lda, const ushort* __restrict__ Bt,
    const float* __restrict__ bias, void* __restrict__ Co, int N, int K) {
  __shared__ ushort As[128 * 64];
  __shared__ ushort Bs[128 * 64];
  const int tid = threadIdx.x;
  const int lane = tid & 63, wid = tid >> 6;
  const int wm = wid >> 1, wn = wid & 1;
  const int l31 = lane & 31, hl = lane >> 5;
  const int bm = blockIdx.y * 128, bn = blockIdx.x * 128;

  f32x16 acc[2][2];
#pragma unroll
  for (int mt = 0; mt < 2; ++mt)
#pragma unroll
    for (int nt = 0; nt < 2; ++nt)
#pragma unroll
      for (int r = 0; r < 16; ++r) acc[mt][nt][r] = 0.f;

  for (int k0 = 0; k0 < K; k0 += 64) {
    __syncthreads();  // all waves done reading LDS from previous K-step
#pragma unroll
    for (int p = 0; p < 4; ++p) {
      const int v = tid + p * 256;
      const int r = v >> 3, sl = (v & 7) ^ (r & 7);  // logical 16B slot
      gload_lds16(A + (size_t)(bm + r) * lda + k0 + sl * 8, As + v * 8);
    }
#pragma unroll
    for (int p = 0; p < 4; ++p) {
      const int v = tid + p * 256;
      const int r = v >> 3, sl = (v & 7) ^ (r & 7);
      gload_lds16(Bt + (size_t)(bn + r) * K + k0 + sl * 8, Bs + v * 8);
    }
    __syncthreads();  // compiler drains vmcnt(0) before this barrier
#pragma unroll
    for (int ks = 0; ks < 4; ++ks) {
      short8 af[2], bf[2];
      const int cb = ks * 32 + hl * 16;  // col-byte within 128B row
#pragma unroll
      for (int mt = 0; mt < 2; ++mt) {
        const int row = wm * 64 + mt * 32 + l31;
        af[mt] = *(const short8*)((const char*)As + row * 128 + (cb ^ ((row & 7) << 4)));
      }
#pragma unroll
      for (int nt = 0; nt < 2; ++nt) {
        const int col = wn * 64 + nt * 32 + l31;
        bf[nt] = *(const short8*)((const char*)Bs + col * 128 + (cb ^ ((col & 7) << 4)));
      }
#pragma unroll
      for (int mt = 0; mt < 2; ++mt)
#pragma unroll
        for (int nt = 0; nt < 2; ++nt)
          acc[mt][nt] = __builtin_amdgcn_mfma_f32_32x32x16_bf16(af[mt], bf[nt],
                                                                acc[mt][nt], 0, 0, 0);
    }
  }

  // epilogue: C row=(r&3)+8*(r>>2)+4*hl (+32mt+64wm), col=l31 (+32nt+64wn)
  const float kinv = (RD != 0) ? (9.210340371976184f / (float)RD) : 0.f;
#pragma unroll
  for (int mt = 0; mt < 2; ++mt)
#pragma unroll
    for (int nt = 0; nt < 2; ++nt) {
      const int col = bn + wn * 64 + nt * 32 + l31;
      const float bi = bias ? bias[col] : 0.f;
      float th = 0.f;
      if constexpr (RD != 0) th = expf(-(float)(col >> 1) * kinv);
#pragma unroll
      for (int r = 0; r < 16; ++r) {
        const int row = bm + wm * 64 + mt * 32 + ((r & 3) + 8 * (r >> 2) + 4 * hl);
        float v = acc[mt][nt][r] + bi;
        if constexpr (RD != 0) {
          const int t = row & (TT - 1);
          float sn, cs;
          sincosf((float)(t + 1) * th, &sn, &cs);
          const float pv = __shfl_xor(v, 1);  // partner column (lane^1)
          v = (l31 & 1) ? (v * cs + pv * sn) : (v * cs - pv * sn);
        }
        if constexpr (OM == 2) v *= QSCALE;
        if constexpr (OM == 0)
          ((float*)Co)[(size_t)row * N + col] = v;
        else
          ((ushort*)Co)[(size_t)row * N + col] = bfu(v);
      }
    }
}

// ---------------------------------------------------------------------------
// small fp32-accum GEMM for kR (N=64): A bf16, W fp32 KxN, RoPE64, bf16 out.
__global__ __launch_bounds__(256) void gemm64_kernel(
    const ushort* __restrict__ A, int lda, const float* __restrict__ W,
    const float* __restrict__ bias, ushort* __restrict__ Co, int N, int K) {
  __shared__ float As[16][68];
  __shared__ float Bs[16][68];
  const int tid = threadIdx.x;
  const int tx = tid & 15, ty = tid >> 4;
  const int bm = blockIdx.y * 64;
  float acc[4][4] = {};

  for (int k0 = 0; k0 < K; k0 += 16) {
    const ushort4 au = *(const ushort4*)(A + (size_t)(bm + (tid >> 2)) * lda + k0 + (tid & 3) * 4);
    const float4 bv = *(const float4*)(W + (size_t)(k0 + (tid >> 4)) * N + (tid & 15) * 4);
    __syncthreads();
    const int ak = (tid & 3) * 4, arr = tid >> 2;
    As[ak + 0][arr] = bf2f(au.x);
    As[ak + 1][arr] = bf2f(au.y);
    As[ak + 2][arr] = bf2f(au.z);
    As[ak + 3][arr] = bf2f(au.w);
    *(float4*)&Bs[tid >> 4][(tid & 15) * 4] = bv;
    __syncthreads();
#pragma unroll
    for (int k = 0; k < 16; ++k) {
      const float4 a = *(const float4*)&As[k][ty * 4];
      const float4 b = *(const float4*)&Bs[k][tx * 4];
      const float avv[4] = {a.x, a.y, a.z, a.w};
      const float bvv[4] = {b.x, b.y, b.z, b.w};
#pragma unroll
      for (int ii = 0; ii < 4; ++ii)
#pragma unroll
        for (int jj = 0; jj < 4; ++jj) acc[ii][jj] += avv[ii] * bvv[jj];
    }
  }

  const int c0 = tx * 4;
  const float4 bi = *(const float4*)(bias + c0);
  const float kinv = 9.210340371976184f / 64.0f;
  const float th0 = expf(-(float)(c0 >> 1) * kinv);
  const float th1 = expf(-(float)((c0 >> 1) + 1) * kinv);
#pragma unroll
  for (int ii = 0; ii < 4; ++ii) {
    const int r = bm + ty * 4 + ii;
    const int t = r & (TT - 1);
    float4 v = make_float4(acc[ii][0] + bi.x, acc[ii][1] + bi.y,
                           acc[ii][2] + bi.z, acc[ii][3] + bi.w);
    float s0, c0_, s1, c1_;
    sincosf((float)(t + 1) * th0, &s0, &c0_);
    sincosf((float)(t + 1) * th1, &s1, &c1_);
    const float4 o = make_float4(v.x * c0_ - v.y * s0, v.y * c0_ + v.x * s0,
                                 v.z * c1_ - v.w * s1, v.w * c1_ + v.z * s1);
    uint2 u;
    u.x = pk2(o.x, o.y);
    u.y = pk2(o.z, o.w);
    *(uint2*)(Co + (size_t)r * N + c0) = u;
  }
}

// ---------------------------------------------------------------------------
// MFMA flash attention (round-3 verified structure). ao out is now bf16.
__global__ __launch_bounds__(256, 2) void flash_kernel(
    const ushort* __restrict__ qarr, const ushort* __restrict__ qRarr,
    const ushort* __restrict__ karr, const ushort* __restrict__ kRarr,
    const ushort* __restrict__ varr, ushort* __restrict__ oarr) {
  __shared__ ushort Ks[64][200];
  __shared__ ushort Vt[128][72];

  const int bi = (int)gridDim.x - 1 - (int)blockIdx.x;
  const int qt0 = bi * 128;
  const int bh = blockIdx.y;
  const int b = bh >> 4, hh = bh & 15;
  const int tid = threadIdx.x;
  const int lane = tid & 63, wid = tid >> 6;
  const int l31 = lane & 31, hl = lane >> 5;
  const int qbase = qt0 + wid * 32;
  const size_t rowbase = (size_t)b * TT;

  short8 qf[12];
  {
    const ushort* qp  = qarr  + (rowbase + qbase + l31) * 2048 + hh * 128;
    const ushort* qRp = qRarr + (rowbase + qbase + l31) * 1024 + hh * 64;
#pragma unroll
    for (int ks = 0; ks < 12; ++ks) {
      const int d = ks * 16 + hl * 8;
      const ushort* p = (d < 128) ? (qp + d) : (qRp + (d - 128));
      qf[ks] = *(const short8*)p;
    }
  }

  f32x16 oacc[4];
#pragma unroll
  for (int nt = 0; nt < 4; ++nt)
#pragma unroll
    for (int r = 0; r < 16; ++r) oacc[nt][r] = 0.f;
  float m_run = -1e30f, l_run = 0.f;

  const int nkt = 2 * bi + 2;
  for (int kt = 0; kt < nkt; ++kt) {
    const int kt0 = kt * 64;
    short8 kreg[6], vreg[4];
    {
      const int r = tid >> 2, sub = tid & 3;
      const ushort* kp  = karr  + (rowbase + kt0 + r) * 2048 + hh * 128;
      const ushort* kRp = kRarr + (rowbase + kt0 + r) * 64;
#pragma unroll
      for (int c = 0; c < 6; ++c) {
        const int d0 = c * 32 + sub * 8;
        const ushort* p = (d0 < 128) ? (kp + d0) : (kRp + (d0 - 128));
        kreg[c] = *(const short8*)p;
      }
      const int vr = tid & 63, dblk = tid >> 6;
      const ushort* vp = varr + (rowbase + kt0 + vr) * 2048 + hh * 128 + dblk * 32;
#pragma unroll
      for (int c = 0; c < 4; ++c) vreg[c] = *(const short8*)(vp + c * 8);
    }
    __syncthreads();
    {
      const int r = tid >> 2, sub = tid & 3;
#pragma unroll
      for (int c = 0; c < 6; ++c) *(short8*)&Ks[r][c * 32 + sub * 8] = kreg[c];
      const int vr = tid & 63, dblk = tid >> 6;
#pragma unroll
      for (int c = 0; c < 4; ++c)
#pragma unroll
        for (int e = 0; e < 8; ++e)
          Vt[dblk * 32 + c * 8 + e][vr] = (ushort)vreg[c][e];
    }
    __syncthreads();

    if (kt0 < qbase + 32) {
      f32x16 sa[2];
#pragma unroll
      for (int t2 = 0; t2 < 2; ++t2)
#pragma unroll
        for (int r = 0; r < 16; ++r) sa[t2][r] = 0.f;
#pragma unroll
      for (int ks = 0; ks < 12; ++ks) {
        const short8 ka0 = *(const short8*)&Ks[l31][ks * 16 + hl * 8];
        const short8 ka1 = *(const short8*)&Ks[32 + l31][ks * 16 + hl * 8];
        sa[0] = __builtin_amdgcn_mfma_f32_32x32x16_bf16(ka0, qf[ks], sa[0], 0, 0, 0);
        sa[1] = __builtin_amdgcn_mfma_f32_32x32x16_bf16(ka1, qf[ks], sa[1], 0, 0, 0);
      }
      if (kt0 + 63 > qbase) {
        const int qrow = qbase + l31;
#pragma unroll
        for (int t2 = 0; t2 < 2; ++t2)
#pragma unroll
          for (int r = 0; r < 16; ++r) {
            const int kcol = kt0 + t2 * 32 + (r & 3) + 8 * (r >> 2) + 4 * hl;
            if (kcol > qrow) sa[t2][r] = -1e30f;
          }
      }
      float pmax = -1e30f;
#pragma unroll
      for (int t2 = 0; t2 < 2; ++t2)
#pragma unroll
        for (int r = 0; r < 16; ++r) pmax = fmaxf(pmax, sa[t2][r]);
      pmax = fmaxf(pmax, __shfl_xor(pmax, 32));
      if (!__all(pmax <= m_run + 8.0f)) {
        const float mnew = fmaxf(m_run, pmax);
        const float alpha = __expf(m_run - mnew);
        m_run = mnew;
        l_run *= alpha;
#pragma unroll
        for (int r = 0; r < 16; ++r) {
          const int qr = (r & 3) + 8 * (r >> 2) + 4 * hl;
          const float al = __shfl(alpha, qr);
          oacc[0][r] *= al; oacc[1][r] *= al; oacc[2][r] *= al; oacc[3][r] *= al;
        }
      }
      float rsum = 0.f;
#pragma unroll
      for (int t2 = 0; t2 < 2; ++t2)
#pragma unroll
        for (int r = 0; r < 16; ++r) {
          const float p = __expf(sa[t2][r] - m_run);
          sa[t2][r] = p;
          rsum += p;
        }
      rsum += __shfl_xor(rsum, 32);
      l_run += rsum;
      short8 pf[4];
#pragma unroll
      for (int t2 = 0; t2 < 2; ++t2)
#pragma unroll
        for (int kb = 0; kb < 2; ++kb) {
          const int g = kb * 8;
          unsigned wa = pk2(sa[t2][g + 0], sa[t2][g + 1]);
          unsigned wb = pk2(sa[t2][g + 4], sa[t2][g + 5]);
          unsigned wc = pk2(sa[t2][g + 2], sa[t2][g + 3]);
          unsigned wd = pk2(sa[t2][g + 6], sa[t2][g + 7]);
          asm volatile("v_permlane32_swap_b32 %0, %1" : "+v"(wa), "+v"(wb));
          asm volatile("v_permlane32_swap_b32 %0, %1" : "+v"(wc), "+v"(wd));
          union { unsigned u[4]; short8 s; } cv;
          cv.u[0] = wa; cv.u[1] = wc; cv.u[2] = wb; cv.u[3] = wd;
          pf[t2 * 2 + kb] = cv.s;
        }
#pragma unroll
      for (int ks = 0; ks < 4; ++ks)
#pragma unroll
        for (int nt = 0; nt < 4; ++nt) {
          const short8 vf = *(const short8*)&Vt[nt * 32 + l31][ks * 16 + hl * 8];
          oacc[nt] = __builtin_amdgcn_mfma_f32_32x32x16_bf16(pf[ks], vf, oacc[nt], 0, 0, 0);
        }
    }
  }

  const float inv = 1.0f / l_run;
#pragma unroll
  for (int r = 0; r < 16; ++r) {
    const int qr = (r & 3) + 8 * (r >> 2) + 4 * hl;
    const float il = __shfl(inv, qr);
    ushort* orow = oarr + (rowbase + qbase + qr) * 2048 + hh * 128;
#pragma unroll
    for (int nt = 0; nt < 4; ++nt) orow[nt * 32 + l31] = bfu(oacc[nt][r] * il);
  }
}

// ---------------------------------------------------------------------------
extern "C" void kernel_launch(void* const* d_in, const int* in_sizes, int n_in,
                              void* d_out, int out_size, void* d_ws, size_t ws_size,
                              hipStream_t stream) {
  const float* x   = (const float*)d_in[0];
  const float* WA  = (const float*)d_in[1];
  const float* bA  = (const float*)d_in[2];
  const float* WB  = (const float*)d_in[3];
  const float* bB  = (const float*)d_in[4];
  const float* WC  = (const float*)d_in[5];
  const float* bC  = (const float*)d_in[6];
  const float* WUQ = (const float*)d_in[7];
  const float* WUK = (const float*)d_in[8];
  const float* WUV = (const float*)d_in[9];
  const float* WZ  = (const float*)d_in[10];
  const float* bZ  = (const float*)d_in[11];
  float* out = (float*)d_out;

  // workspace (ushorts), ~130 MB total
  ushort* xb   = (ushort*)d_ws;                 // 4096x2048
  ushort* WAt  = xb   + (size_t)MM * 2048;      // 1024x2048 (WA^T)
  ushort* WCt  = WAt  + (size_t)1024 * 2048;    // 1024x1024
  ushort* WUQt = WCt  + (size_t)1024 * 1024;    // 2048x512
  ushort* WUKt = WUQt + (size_t)2048 * 512;
  ushort* WUVt = WUKt + (size_t)2048 * 512;
  ushort* WZt  = WUVt + (size_t)2048 * 512;     // 2048x2048
  ushort* hb   = WZt  + (size_t)2048 * 2048;    // 4096x1024
  ushort* kR   = hb   + (size_t)MM * 1024;      // 4096x64
  ushort* qR   = kR   + (size_t)MM * 64;        // 4096x1024
  ushort* qb   = qR   + (size_t)MM * 1024;      // 4096x2048
  ushort* kb   = qb   + (size_t)MM * 2048;
  ushort* vb   = kb   + (size_t)MM * 2048;
  ushort* aob  = vb   + (size_t)MM * 2048;

  const dim3 thr(256);

  // ---- prep: bf16 conversions (x flat; weights transposed to NxK)
  conv_kernel<<<dim3((MM * 2048) / 1024), thr, 0, stream>>>(x, xb);
  tconv_kernel<<<dim3(1024 / 64, 2048 / 64), thr, 0, stream>>>(WA, WAt, 2048, 1024);
  tconv_kernel<<<dim3(1024 / 64, 1024 / 64), thr, 0, stream>>>(WC, WCt, 1024, 1024);
  tconv_kernel<<<dim3(2048 / 64, 512 / 64), thr, 0, stream>>>(WUQ, WUQt, 512, 2048);
  tconv_kernel<<<dim3(2048 / 64, 512 / 64), thr, 0, stream>>>(WUK, WUKt, 512, 2048);
  tconv_kernel<<<dim3(2048 / 64, 512 / 64), thr, 0, stream>>>(WUV, WUVt, 512, 2048);
  tconv_kernel<<<dim3(2048 / 64, 2048 / 64), thr, 0, stream>>>(WZ, WZt, 2048, 2048);

  // ---- GEMMs (MFMA bf16)
  // h = x @ WA + bA -> bf16
  gemm_mfma_kernel<0, 1><<<dim3(1024 / 128, MM / 128), thr, 0, stream>>>(
      xb, 2048, WAt, bA, hb, 1024, 2048);
  // kR = rope64(h @ WB + bB) -> bf16 (small, VALU path, fp32 W direct)
  gemm64_kernel<<<dim3(1, MM / 64), thr, 0, stream>>>(hb, 1024, WB, bB, kR, 64, 1024);
  // qR = rope1024(h @ WC + bC) * qscale -> bf16
  gemm_mfma_kernel<1024, 2><<<dim3(1024 / 128, MM / 128), thr, 0, stream>>>(
      hb, 1024, WCt, bC, qR, 1024, 1024);
  // q = (q_lat @ WUQ) * qscale -> bf16   (q_lat = h[:,512:])
  gemm_mfma_kernel<0, 2><<<dim3(2048 / 128, MM / 128), thr, 0, stream>>>(
      hb + 512, 1024, WUQt, nullptr, qb, 2048, 512);
  // k = kv_lat @ WUK -> bf16
  gemm_mfma_kernel<0, 1><<<dim3(2048 / 128, MM / 128), thr, 0, stream>>>(
      hb, 1024, WUKt, nullptr, kb, 2048, 512);
  // v = kv_lat @ WUV -> bf16
  gemm_mfma_kernel<0, 1><<<dim3(2048 / 128, MM / 128), thr, 0, stream>>>(
      hb, 1024, WUVt, nullptr, vb, 2048, 512);
  // ---- flash attention -> ao bf16
  flash_kernel<<<dim3(TT / 128, BB * NHH), thr, 0, stream>>>(qb, qR, kb, kR, vb, aob);
  // ---- out = ao @ WZ + bZ -> fp32
  gemm_mfma_kernel<0, 0><<<dim3(2048 / 128, MM / 128), thr, 0, stream>>>(
      aob, 2048, WZt, bZ, out, 2048, 2048);
}